// Round 2
// baseline (13072.292 us; speedup 1.0000x reference)
//
#include <hip/hip_runtime.h>
#include <math.h>

// ---------- types ----------
typedef _Float16 h8 __attribute__((ext_vector_type(8)));
typedef _Float16 h4 __attribute__((ext_vector_type(4)));
typedef float f16v __attribute__((ext_vector_type(16)));

#define HPS 262144   // plane stride (elems) for [256][1024] hi/lo activation buffers
#define XPS 2097152  // plane stride for x [256][128][64]
#define IPS 16384    // plane stride for xin [256][64]
#define BSTR 40      // LDS row stride in h16 (80B: 16B-aligned for b128 ops)
#define BUFH (256 * BSTR)  // h16 per LDS buffer: 2 planes * 128 cols * 40

__device__ __forceinline__ float4 ld4(const float* p) { return *(const float4*)p; }
__device__ __forceinline__ float sigf(float x) { return 1.0f / (1.0f + expf(-x)); }
__device__ __forceinline__ float bf2f(unsigned short u) { return __uint_as_float(((unsigned)u) << 16); }
__device__ __forceinline__ float rdin(const void* p, size_t i, int bf) {
  return bf ? bf2f(((const unsigned short*)p)[i]) : ((const float*)p)[i];
}

// ---------- input dtype detector ----------
__global__ void detect_dtype(const unsigned short* __restrict__ probe, int n, int* flag) {
  __shared__ int cnt;
  if (threadIdx.x == 0) cnt = 0;
  __syncthreads();
  int c = 0;
  for (int i = threadIdx.x; i < n; i += 256) {
    int e = (probe[i] >> 7) & 0xFF;
    if (e >= 100 && e <= 126) c++;
  }
  atomicAdd(&cnt, c);
  __syncthreads();
  if (threadIdx.x == 0) *flag = (cnt > (n * 3) / 4) ? 1 : 0;
}

// ---------- dual-mode fp32 convert (biases) ----------
__global__ void cvt_f32(const void* __restrict__ in, float* __restrict__ out, int n,
                        const int* __restrict__ flag) {
  int bf = *flag;
  int i = blockIdx.x * 256 + threadIdx.x;
  if (i < n) out[i] = rdin(in, i, bf);
}

// ---------- transpose + fp16 hi/lo split of weights ----------
__global__ void tsplit(const void* __restrict__ in, int N,
                       _Float16* __restrict__ outHi, _Float16* __restrict__ outLo,
                       int ldo, int kOff, int pOff, const int* __restrict__ flag) {
  __shared__ float tile[32][33];
  int bf = *flag;
  int kb = blockIdx.x * 32, nb = blockIdx.y * 32;
  for (int r = threadIdx.y; r < 32; r += 8)
    tile[threadIdx.x][r] = rdin(in, (size_t)(kb + r) * N + nb + threadIdx.x, bf);
  __syncthreads();
  for (int r = threadIdx.y; r < 32; r += 8) {
    float v = tile[r][threadIdx.x];
    _Float16 hi = (_Float16)v;
    _Float16 lo = (_Float16)(v - (float)hi);
    size_t o = (size_t)(pOff + nb + r) * ldo + kOff + kb + threadIdx.x;
    outHi[o] = hi; outLo[o] = lo;
  }
}

// input -> hi/lo fp16 planes
__global__ void f2h_kernel(const void* __restrict__ in, _Float16* __restrict__ out, int n,
                           const int* __restrict__ flag) {
  int bf = *flag;
  int i = blockIdx.x * 1024 + threadIdx.x * 4;
  if (i < n) {
    float vv[4];
#pragma unroll
    for (int k = 0; k < 4; ++k) vv[k] = rdin(in, i + k, bf);
    h4 hv, lv;
#pragma unroll
    for (int k = 0; k < 4; ++k) { hv[k] = (_Float16)vv[k]; lv[k] = (_Float16)(vv[k] - (float)hv[k]); }
    *(h4*)(out + i) = hv;
    *(h4*)(out + n + i) = lv;
  }
}

__global__ void sentinel_kernel(float* out, float v) { out[0] = v; }

// ---------- core GEMM tile ----------
// Block tile = 256 rows x 128 cols. 4 waves in 2x2: wave (wm,wn) owns 128 rows x 64 cols
// => R=4 row-blocks x C=2 col-blocks of 32x32 MFMA tiles.
// Per 32-K chunk: 48 MFMA (384cy) vs 8 ds_read_b128/wave (256cy/CU) -> MFMA-bound.
// LDS double-buffered: ONE barrier per chunk; next chunk's B prefetched into regs
// under the MFMAs. 3 passes: Ah*Wh + Ah*Wl + Al*Wh (fp32-accurate f16 emulation).
__device__ __forceinline__ void gemm_tile(
    const _Float16* __restrict__ A0, int lda0, int aps0,
    const _Float16* __restrict__ A1, int lda1, int aps1, int ksplit,
    const _Float16* __restrict__ WTh, const _Float16* __restrict__ WTl, int ldw,
    int pbase, int c0, int c1,
    float* __restrict__ zp, int zld, _Float16* Bs /* [2][2*128][BSTR] */) {
  const int tid = threadIdx.x;
  const int wv = tid >> 6, lane = tid & 63;
  const int wm = wv >> 1, wn = wv & 1;
  const int l31 = lane & 31, lhi = lane >> 5;

  f16v acc[4][2] = {{{}, {}}, {{}, {}}, {{}, {}}, {{}, {}}};

  const _Float16* a0p[4];
  const _Float16* a1p[4];
#pragma unroll
  for (int rb = 0; rb < 4; ++rb) {
    int r = wm * 128 + rb * 32 + l31;
    a0p[rb] = A0 + (size_t)r * lda0;
    a1p[rb] = A1 + (size_t)r * lda1;
  }

  // staging roles: thread t loads (plane = t>>7, WT row = t&127), 64B per chunk
  const int spl = tid >> 7;
  const int srow = tid & 127;
  const _Float16* sbase = (spl ? WTl : WTh) + (size_t)(pbase + srow) * ldw;
  const int sdoff = (spl * 128 + srow) * BSTR;

  // prologue: stage chunk c0 into buffer 0
  {
    const _Float16* s = sbase + (c0 << 5);
    float4 v0 = *(const float4*)(s);
    float4 v1 = *(const float4*)(s + 8);
    float4 v2 = *(const float4*)(s + 16);
    float4 v3 = *(const float4*)(s + 24);
    _Float16* d = Bs + sdoff;
    *(float4*)(d) = v0;      *(float4*)(d + 8) = v1;
    *(float4*)(d + 16) = v2; *(float4*)(d + 24) = v3;
  }

  int buf = 0;
  for (int c = c0; c < c1; ++c) {
    __syncthreads();  // buf's writes (prev iter / prologue) visible; prev reads of buf^1 done
    float4 n0, n1, n2, n3;
    const bool more = (c + 1 < c1);
    if (more) {
      const _Float16* s = sbase + ((c + 1) << 5);
      n0 = *(const float4*)(s);
      n1 = *(const float4*)(s + 8);
      n2 = *(const float4*)(s + 16);
      n3 = *(const float4*)(s + 24);
    }
    const _Float16* bb = Bs + buf * BUFH;
#pragma unroll
    for (int sub = 0; sub < 2; ++sub) {
      int ks = (c << 5) + sub * 16 + lhi * 8;
      int kl = sub * 16 + lhi * 8;
      h8 bh[2], bl[2];
#pragma unroll
      for (int cb = 0; cb < 2; ++cb) {
        int colrow = wn * 64 + cb * 32 + l31;
        bh[cb] = *(const h8*)(bb + (size_t)colrow * BSTR + kl);
        bl[cb] = *(const h8*)(bb + (size_t)(128 + colrow) * BSTR + kl);
      }
      h8 ah[4], al[4];
#pragma unroll
      for (int rb = 0; rb < 4; ++rb) {
        const _Float16* pa; int ap;
        if (ks < ksplit) { pa = a0p[rb] + ks; ap = aps0; }
        else             { pa = a1p[rb] + (ks - ksplit); ap = aps1; }
        ah[rb] = *(const h8*)pa;
        al[rb] = *(const h8*)(pa + ap);
      }
#pragma unroll
      for (int rb = 0; rb < 4; ++rb)
#pragma unroll
        for (int cb = 0; cb < 2; ++cb)
          acc[rb][cb] = __builtin_amdgcn_mfma_f32_32x32x16_f16(ah[rb], bh[cb], acc[rb][cb], 0, 0, 0);
#pragma unroll
      for (int rb = 0; rb < 4; ++rb)
#pragma unroll
        for (int cb = 0; cb < 2; ++cb)
          acc[rb][cb] = __builtin_amdgcn_mfma_f32_32x32x16_f16(ah[rb], bl[cb], acc[rb][cb], 0, 0, 0);
#pragma unroll
      for (int rb = 0; rb < 4; ++rb)
#pragma unroll
        for (int cb = 0; cb < 2; ++cb)
          acc[rb][cb] = __builtin_amdgcn_mfma_f32_32x32x16_f16(al[rb], bh[cb], acc[rb][cb], 0, 0, 0);
    }
    if (more) {
      _Float16* d = Bs + (buf ^ 1) * BUFH + sdoff;
      *(float4*)(d) = n0;      *(float4*)(d + 8) = n1;
      *(float4*)(d + 16) = n2; *(float4*)(d + 24) = n3;
    }
    buf ^= 1;
  }

  // epilogue. C/D layout (verified m74/m101): col = lane&31, row = (reg&3)+8*(reg>>2)+4*(lane>>5)
#pragma unroll
  for (int rb = 0; rb < 4; ++rb) {
#pragma unroll
    for (int cb = 0; cb < 2; ++cb) {
      int col = pbase + wn * 64 + cb * 32 + l31;
#pragma unroll
      for (int r = 0; r < 16; ++r) {
        int row = wm * 128 + rb * 32 + (r & 3) + ((r >> 2) * 8) + lhi * 4;
        zp[(size_t)row * zld + col] = acc[rb][cb][r];
      }
    }
  }
}

// ---------- encoder GEMM: L1(t-1) first (longest), then L0(t), then KV(t-2) ----------
__global__ __launch_bounds__(256) void enc_gemm(int t, int l1kq,
    const _Float16* xh, const _Float16* h0, const _Float16* h1,
    const _Float16* wt0h, const _Float16* wt0l,
    const _Float16* wt1h, const _Float16* wt1l,
    const _Float16* wtkvh, const _Float16* wtkvl,
    float* z0, float* z1, float* kvz) {
  __shared__ _Float16 Bs[2 * BUFH];
  int blk = blockIdx.x;
  int nl1 = 32 * l1kq;
  if (blk < nl1) {                       // L1, timestep t-1
    if (t < 1 || t > 128) return;
    int pg = blk & 31, kq = blk >> 5;
    int c0 = (64 * kq) / l1kq, c1 = (64 * (kq + 1)) / l1kq;
    gemm_tile(h0, 1024, HPS, h1, 1024, HPS, 1024, wt1h, wt1l, 2048,
              pg * 128, c0, c1, z1 + (size_t)kq * 1048576, 4096, Bs);
  } else if (blk < nl1 + 64) {           // L0, timestep t
    if (t > 127) return;
    int w = blk - nl1, pg = w & 31, kq = w >> 5;
    gemm_tile(xh + (size_t)t * 64, 8192, XPS, h0, 1024, HPS, 64, wt0h, wt0l, 1088,
              pg * 128, kq * 17, kq * 17 + 17, z0 + (size_t)kq * 1048576, 4096, Bs);
  } else {                               // KV, timestep t-2
    if (t < 2) return;
    int w = blk - nl1 - 64, pg = w & 15, kq = w >> 4;
    gemm_tile(h1, 1024, HPS, h1, 1024, HPS, 1024, wtkvh, wtkvl, 1024,
              pg * 128, kq * 16, kq * 16 + 16, kvz + (size_t)kq * 524288, 2048, Bs);
  }
}

// ---------- generic K-split GEMM (decoder stages) ----------
__global__ __launch_bounds__(256) void gemm_k(
    const _Float16* A0, int lda0, int aps0,
    const _Float16* A1, int lda1, int aps1, int ksplit,
    const _Float16* WTh, const _Float16* WTl, int ldw,
    int npg, int nkq, int tot, int kqoff, float* zp, int zld) {
  __shared__ _Float16 Bs[2 * BUFH];
  int pg = blockIdx.x % npg, kq = blockIdx.x / npg + kqoff;
  int c0 = (tot * kq) / nkq, c1 = (tot * (kq + 1)) / nkq;
  gemm_tile(A0, lda0, aps0, A1, lda1, aps1, ksplit, WTh, WTl, ldw,
            pg * 128, c0, c1, zp + (size_t)kq * 256 * zld, zld, Bs);
}

// ---------- fused q-projection + fc top-half (both depend only on dh1) ----------
__global__ __launch_bounds__(256) void qfc_kernel(
    const _Float16* h1,
    const _Float16* wqh, const _Float16* wql,
    const _Float16* wfh, const _Float16* wfl,
    float* qp, float* fcp) {
  __shared__ _Float16 Bs[2 * BUFH];
  int blk = blockIdx.x;
  if (blk < 32) {           // q = dh1 @ Wq : N=1024, K=1024
    int pg = blk & 7, kq = blk >> 3;
    gemm_tile(h1, 1024, HPS, h1, 1024, HPS, 1024, wqh, wql, 1024,
              pg * 128, kq * 8, kq * 8 + 8, qp + (size_t)kq * 262144, 1024, Bs);
  } else {                  // fc top: chunks [0,32) = dh1 half of fc_W (parts 0..3)
    int w = blk - 32, pg = w & 7, kq = w >> 3;
    gemm_tile(h1, 1024, HPS, h1, 1024, HPS, 1024, wfh, wfl, 2048,
              pg * 128, kq * 8, kq * 8 + 8, fcp + (size_t)kq * 262144, 1024, Bs);
  }
}

// ---------- LSTM gate pointwise ----------
__device__ __forceinline__ void gates_body(const float* __restrict__ zp, int nparts,
    const float* __restrict__ bias, float* __restrict__ c,
    _Float16* __restrict__ h, int blk) {
  int e = blk * 1024 + threadIdx.x * 4;
  int b = e >> 10, j = e & 1023;
  size_t zrow = (size_t)b * 4096;
  float4 vi = ld4(bias + j), vf = ld4(bias + 1024 + j), vg = ld4(bias + 2048 + j), vo = ld4(bias + 3072 + j);
  for (int q = 0; q < nparts; ++q) {
    const float* zq = zp + (size_t)q * 1048576 + zrow;
    float4 t;
    t = ld4(zq + j);        vi.x += t.x; vi.y += t.y; vi.z += t.z; vi.w += t.w;
    t = ld4(zq + 1024 + j); vf.x += t.x; vf.y += t.y; vf.z += t.z; vf.w += t.w;
    t = ld4(zq + 2048 + j); vg.x += t.x; vg.y += t.y; vg.z += t.z; vg.w += t.w;
    t = ld4(zq + 3072 + j); vo.x += t.x; vo.y += t.y; vo.z += t.z; vo.w += t.w;
  }
  float* cp = c + (size_t)b * 1024 + j;
  float4 cv = ld4(cp);
  float zi[4] = {vi.x, vi.y, vi.z, vi.w}, zf[4] = {vf.x, vf.y, vf.z, vf.w};
  float zg[4] = {vg.x, vg.y, vg.z, vg.w}, zo[4] = {vo.x, vo.y, vo.z, vo.w};
  float cc[4] = {cv.x, cv.y, cv.z, cv.w};
  float hn[4];
#pragma unroll
  for (int k = 0; k < 4; ++k) {
    float ii = sigf(zi[k]), ff = sigf(zf[k]), gg = tanhf(zg[k]), oo = sigf(zo[k]);
    float cn = ff * cc[k] + ii * gg;
    cc[k] = cn;
    hn[k] = oo * tanhf(cn);
  }
  float4 co; co.x = cc[0]; co.y = cc[1]; co.z = cc[2]; co.w = cc[3];
  *(float4*)cp = co;
  h4 hv, lv;
#pragma unroll
  for (int k = 0; k < 4; ++k) { hv[k] = (_Float16)hn[k]; lv[k] = (_Float16)(hn[k] - (float)hv[k]); }
  *(h4*)(h + (size_t)b * 1024 + j) = hv;
  *(h4*)(h + HPS + (size_t)b * 1024 + j) = lv;
}

// grid 1024: [0,256) L0 gates, [256,512) L1 gates, [512,1024) KV bias+fp16 store
__global__ void enc_gates(int t, int l1parts, const float* z0, const float* z1, const float* kvz,
                          const float* b0, const float* b1,
                          const float* bk, const float* bv,
                          float* c0, float* c1, _Float16* h0, _Float16* h1,
                          _Float16* Kp, _Float16* Vp) {
  int blk = blockIdx.x;
  if (blk < 256) {
    if (t > 127) return;
    gates_body(z0, 2, b0, c0, h0, blk);
  } else if (blk < 512) {
    if (t < 1 || t > 128) return;
    gates_body(z1, l1parts, b1, c1, h1, blk - 256);
  } else {
    if (t < 2) return;
    int e = (blk - 512) * 1024 + threadIdx.x * 4;   // [0, 524288) = [256][2048]
    int b = e >> 11, col = e & 2047;
    const float* bb = (col < 1024) ? (bk + col) : (bv + col - 1024);
    float4 v = ld4(bb);
    for (int q = 0; q < 2; ++q) {
      float4 tt = ld4(kvz + (size_t)q * 524288 + e);
      v.x += tt.x; v.y += tt.y; v.z += tt.z; v.w += tt.w;
    }
    _Float16* dst = (col < 1024) ? Kp : Vp;
    int cc = (col < 1024) ? col : col - 1024;
    h4 hv; hv[0] = (_Float16)v.x; hv[1] = (_Float16)v.y; hv[2] = (_Float16)v.z; hv[3] = (_Float16)v.w;
    *(h4*)(dst + (size_t)(b * 128 + (t - 2)) * 1024 + cc) = hv;
  }
}

__global__ void dec_gates(const float* zp, int nparts, const float* bias,
                          float* c, _Float16* h) {
  gates_body(zp, nparts, bias, c, h, blockIdx.x);
}

// ---------- reduce + bias (+relu) -> hi/lo fp16, cols = 1024 ----------
__global__ void reduce_act(const float* __restrict__ zp, int nparts,
                           const float* __restrict__ bias, _Float16* __restrict__ out, int relu) {
  int e = blockIdx.x * 1024 + threadIdx.x * 4;
  int j = e & 1023;
  float4 v = ld4(bias + j);
  for (int q = 0; q < nparts; ++q) {
    float4 t = ld4(zp + (size_t)q * 262144 + e);
    v.x += t.x; v.y += t.y; v.z += t.z; v.w += t.w;
  }
  if (relu) {
    v.x = fmaxf(v.x, 0.f); v.y = fmaxf(v.y, 0.f); v.z = fmaxf(v.z, 0.f); v.w = fmaxf(v.w, 0.f);
  }
  float vv[4] = {v.x, v.y, v.z, v.w};
  h4 hv, lv;
#pragma unroll
  for (int k = 0; k < 4; ++k) { hv[k] = (_Float16)vv[k]; lv[k] = (_Float16)(vv[k] - (float)hv[k]); }
  *(h4*)(out + e) = hv;
  *(h4*)(out + HPS + e) = lv;
}

// ---------- final output: reduce 16 parts (zld=128, cols 0..63 valid) ----------
__global__ void out_reduce(const float* __restrict__ op, const float* __restrict__ outb,
                           float* __restrict__ dout, _Float16* __restrict__ xin, int s) {
  int e = blockIdx.x * 1024 + threadIdx.x * 4;  // 16 blocks -> 16384 elems
  int b = e >> 6, o = e & 63;
  float4 v = ld4(outb + o);
  for (int q = 0; q < 16; ++q) {
    float4 t = ld4(op + (size_t)q * 32768 + b * 128 + o);
    v.x += t.x; v.y += t.y; v.z += t.z; v.w += t.w;
  }
  *(float4*)(dout + (size_t)(b * 16 + s) * 64 + o) = v;   // d_out is fp32
  float vv[4] = {v.x, v.y, v.z, v.w};
  h4 hv, lv;
#pragma unroll
  for (int k = 0; k < 4; ++k) { hv[k] = (_Float16)vv[k]; lv[k] = (_Float16)(vv[k] - (float)hv[k]); }
  *(h4*)(xin + e) = hv;
  *(h4*)(xin + IPS + e) = lv;
}

// ---------- fused attention ----------
__global__ void attn_kernel(const float* __restrict__ qp, const float* __restrict__ bq,
                            const _Float16* __restrict__ Kp, const _Float16* __restrict__ Vp,
                            _Float16* __restrict__ ctx) {
  int b = blockIdx.x >> 2, n = blockIdx.x & 3;
  __shared__ float qs[256];
  __shared__ float sw[128];
  int tid = threadIdx.x;
  float qv = bq[n * 256 + tid];
  for (int q = 0; q < 4; ++q) qv += qp[(size_t)q * 262144 + (size_t)b * 1024 + n * 256 + tid];
  qs[tid] = qv;
  __syncthreads();
  int w = tid >> 6, lane = tid & 63;
  for (int s = w; s < 128; s += 4) {
    const _Float16* kr = Kp + (size_t)(b * 128 + s) * 1024 + n * 256;
    float acc = 0.f;
#pragma unroll
    for (int d = 0; d < 4; ++d) acc += qs[lane + d * 64] * (float)kr[lane + d * 64];
    for (int off = 32; off; off >>= 1) acc += __shfl_down(acc, off);
    if (lane == 0) sw[s] = acc * 0.0625f;  // / sqrt(256)
  }
  __syncthreads();
  if (w == 0) {
    float a = sw[lane], bb = sw[lane + 64];
    float m = fmaxf(a, bb);
    for (int off = 32; off; off >>= 1) m = fmaxf(m, __shfl_down(m, off));
    m = __shfl(m, 0);
    float e1 = expf(a - m), e2 = expf(bb - m);
    float ss = e1 + e2;
    for (int off = 32; off; off >>= 1) ss += __shfl_down(ss, off);
    ss = __shfl(ss, 0);
    float inv = 1.0f / ss;
    sw[lane] = e1 * inv; sw[lane + 64] = e2 * inv;
  }
  __syncthreads();
  float acc = 0.f;
  const _Float16* vb = Vp + (size_t)b * 131072 + n * 256 + tid;
  for (int s2 = 0; s2 < 128; ++s2) acc += sw[s2] * (float)vb[(size_t)s2 * 1024];
  size_t idx = (size_t)b * 1024 + n * 256 + tid;
  _Float16 hi = (_Float16)acc;
  ctx[idx] = hi;
  ctx[HPS + idx] = (_Float16)(acc - (float)hi);
}

// ---------- host ----------
extern "C" void kernel_launch(void* const* d_in, const int* in_sizes, int n_in,
                              void* d_out, int out_size, void* d_ws, size_t ws_size,
                              hipStream_t stream) {
  const void* x     = d_in[0];
  const void* e0_Wx = d_in[1];
  const void* e0_Wh = d_in[2];
  const void* e0_b  = d_in[3];
  const void* e1_Wx = d_in[4];
  const void* e1_Wh = d_in[5];
  const void* e1_b  = d_in[6];
  const void* d0_Wx = d_in[7];
  const void* d0_Wh = d_in[8];
  const void* d0_b  = d_in[9];
  const void* d1_Wx = d_in[10];
  const void* d1_Wh = d_in[11];
  const void* d1_b  = d_in[12];
  const void* Wq = d_in[13];
  const void* Wk = d_in[14];
  const void* Wv = d_in[15];
  const void* Wo = d_in[16];
  const void* bq = d_in[17];
  const void* bk = d_in[18];
  const void* bv = d_in[19];
  const void* bo = d_in[20];
  const void* fc_W  = d_in[21];
  const void* fc_b  = d_in[22];
  const void* out_W = d_in[23];
  const void* out_b = d_in[24];

  // Layout (retry with smaller L1 K-split if workspace is tight)
  int l1parts = 4;
  char* p = (char*)d_ws;
  int* flag; float* bias_arena; char* warena; char* zero0;
  _Float16 *h0, *h1, *xin, *Kp, *Vp, *ctx, *attn_h, *comb;
  float *c0, *c1; float* zarena;
  size_t zeroBytes = 0;

  for (int attempt = 0; attempt < 2; ++attempt) {
    p = (char*)d_ws;
    auto alloc = [&](size_t bytes) { char* r = p; p += (bytes + 255) & ~(size_t)255; return r; };
    flag = (int*)alloc(256);
    bias_arena = (float*)alloc(87040);
    warena = alloc(68681728);   // wt_out doubled to 128 rows (padded)
    zero0 = p;
    h0 = (_Float16*)alloc(1048576);
    h1 = (_Float16*)alloc(1048576);
    c0 = (float*)alloc(1048576);
    c1 = (float*)alloc(1048576);
    xin = (_Float16*)alloc(65536);
    zeroBytes = (size_t)(p - zero0);
    Kp = (_Float16*)alloc(67108864);
    Vp = (_Float16*)alloc(67108864);
    zarena = (float*)alloc((size_t)(3 + l1parts) * 4194304);
    ctx    = (_Float16*)alloc(1048576);
    attn_h = (_Float16*)alloc(1048576);
    comb   = (_Float16*)alloc(1048576);
    if ((size_t)(p - (char*)d_ws) <= ws_size) break;
    l1parts = 2;
  }
  if ((size_t)(p - (char*)d_ws) > ws_size) {
    sentinel_kernel<<<1, 1, 0, stream>>>((float*)d_out, 1.0e9f + (float)ws_size);
    return;
  }

  float* c_e0b = bias_arena +     0;
  float* c_e1b = bias_arena +  4096;
  float* c_d0b = bias_arena +  8192;
  float* c_d1b = bias_arena + 12288;
  float* c_bq  = bias_arena + 16384;
  float* c_bk  = bias_arena + 17408;
  float* c_bv  = bias_arena + 18432;
  float* c_bo  = bias_arena + 19456;
  float* c_fcb = bias_arena + 20480;
  float* c_ob  = bias_arena + 21504;

  _Float16* wt_e0h = (_Float16*)(warena);
  _Float16* wt_e0l = (_Float16*)(warena +  8912896);
  _Float16* wt_e1h = (_Float16*)(warena + 17825792);
  _Float16* wt_e1l = (_Float16*)(warena + 34603008);
  _Float16* wt_kvh = (_Float16*)(warena + 51380224);
  _Float16* wt_kvl = (_Float16*)(warena + 55574528);
  _Float16* xh     = (_Float16*)(warena + 59768832);
  _Float16* wt_d0h = (_Float16*)(warena);
  _Float16* wt_d0l = (_Float16*)(warena +  8912896);
  _Float16* wt_d1h = (_Float16*)(warena + 17825792);
  _Float16* wt_d1l = (_Float16*)(warena + 34603008);
  _Float16* wt_qh  = (_Float16*)(warena + 51380224);
  _Float16* wt_ql  = (_Float16*)(warena + 53477376);
  _Float16* wt_oh  = (_Float16*)(warena + 55574528);
  _Float16* wt_ol  = (_Float16*)(warena + 57671680);
  _Float16* wt_fch = (_Float16*)(warena + 59768832);
  _Float16* wt_fcl = (_Float16*)(warena + 63963136);
  _Float16* wt_outh= (_Float16*)(warena + 68157440);   // 128x1024 h16 (rows 64..127 zero pad)
  _Float16* wt_outl= (_Float16*)(warena + 68419584);

  float* z0e = zarena;                               // enc L0: 2 parts x 1,048,576 floats
  float* z1e = zarena + 2097152;                     // enc L1: l1parts parts
  float* kvz = z1e + (size_t)l1parts * 1048576;      // enc KV: 2 parts x 524,288 floats
  float* zdec = zarena;                              // dec d0/d1: 4 parts x 1,048,576 floats
  float* fcp = zarena;                               // 8 parts x 262,144 floats
  float* qp  = zarena + 2097152;                     // 4 parts x 262,144 floats
  float* op  = zarena + 3145728;                     // 16 parts x 32,768 floats

  // dtype detection + bias conversion
  detect_dtype<<<1, 256, 0, stream>>>((const unsigned short*)e0_Wx, 16384, flag);
  cvt_f32<<<16, 256, 0, stream>>>(e0_b, c_e0b, 4096, flag);
  cvt_f32<<<16, 256, 0, stream>>>(e1_b, c_e1b, 4096, flag);
  cvt_f32<<<16, 256, 0, stream>>>(d0_b, c_d0b, 4096, flag);
  cvt_f32<<<16, 256, 0, stream>>>(d1_b, c_d1b, 4096, flag);
  cvt_f32<<<4, 256, 0, stream>>>(bq, c_bq, 1024, flag);
  cvt_f32<<<4, 256, 0, stream>>>(bk, c_bk, 1024, flag);
  cvt_f32<<<4, 256, 0, stream>>>(bv, c_bv, 1024, flag);
  cvt_f32<<<4, 256, 0, stream>>>(bo, c_bo, 1024, flag);
  cvt_f32<<<4, 256, 0, stream>>>(fc_b, c_fcb, 1024, flag);
  cvt_f32<<<1, 64, 0, stream>>>(out_b, c_ob, 64, flag);

  dim3 tb(32, 8);
  // encoder weight prep
  tsplit<<<dim3(2, 128), tb, 0, stream>>>(e0_Wx, 4096, wt_e0h, wt_e0l, 1088, 0, 0, flag);
  tsplit<<<dim3(32, 128), tb, 0, stream>>>(e0_Wh, 4096, wt_e0h, wt_e0l, 1088, 64, 0, flag);
  tsplit<<<dim3(32, 128), tb, 0, stream>>>(e1_Wx, 4096, wt_e1h, wt_e1l, 2048, 0, 0, flag);
  tsplit<<<dim3(32, 128), tb, 0, stream>>>(e1_Wh, 4096, wt_e1h, wt_e1l, 2048, 1024, 0, flag);
  tsplit<<<dim3(32, 32), tb, 0, stream>>>(Wk, 1024, wt_kvh, wt_kvl, 1024, 0, 0, flag);
  tsplit<<<dim3(32, 32), tb, 0, stream>>>(Wv, 1024, wt_kvh, wt_kvl, 1024, 0, 1024, flag);
  f2h_kernel<<<2048, 256, 0, stream>>>(x, xh, 2097152, flag);
  hipMemsetAsync(zero0, 0, zeroBytes, stream);

  // encoder: L1(t-1) || L0(t) || KV(t-2) pipelined
  int encBlocks = 32 * l1parts + 96;
  for (int t = 0; t <= 129; ++t) {
    enc_gemm<<<encBlocks, 256, 0, stream>>>(t, l1parts, xh, h0, h1,
                                            wt_e0h, wt_e0l, wt_e1h, wt_e1l,
                                            wt_kvh, wt_kvl, z0e, z1e, kvz);
    enc_gates<<<1024, 256, 0, stream>>>(t, l1parts, z0e, z1e, kvz, c_e0b, c_e1b, c_bk, c_bv,
                                        c0, c1, h0, h1, Kp, Vp);
  }

  // decoder weight prep (overwrites encoder weights; stream-ordered)
  tsplit<<<dim3(2, 128), tb, 0, stream>>>(d0_Wx, 4096, wt_d0h, wt_d0l, 1088, 0, 0, flag);
  tsplit<<<dim3(32, 128), tb, 0, stream>>>(d0_Wh, 4096, wt_d0h, wt_d0l, 1088, 64, 0, flag);
  tsplit<<<dim3(32, 128), tb, 0, stream>>>(d1_Wx, 4096, wt_d1h, wt_d1l, 2048, 0, 0, flag);
  tsplit<<<dim3(32, 128), tb, 0, stream>>>(d1_Wh, 4096, wt_d1h, wt_d1l, 2048, 1024, 0, flag);
  tsplit<<<dim3(32, 32), tb, 0, stream>>>(Wq, 1024, wt_qh, wt_ql, 1024, 0, 0, flag);
  tsplit<<<dim3(32, 32), tb, 0, stream>>>(Wo, 1024, wt_oh, wt_ol, 1024, 0, 0, flag);
  tsplit<<<dim3(64, 32), tb, 0, stream>>>(fc_W, 1024, wt_fch, wt_fcl, 2048, 0, 0, flag);
  tsplit<<<dim3(32, 2), tb, 0, stream>>>(out_W, 64, wt_outh, wt_outl, 1024, 0, 0, flag);
  hipMemsetAsync(wt_outh + 65536, 0, 131072, stream);   // pad rows 64..127
  hipMemsetAsync(wt_outl + 65536, 0, 131072, stream);

  // decoder: 16 steps
  for (int s = 0; s < 16; ++s) {
    gemm_k<<<128, 256, 0, stream>>>(xin, 64, IPS, h0, 1024, HPS, 64,
                                    wt_d0h, wt_d0l, 1088, 32, 4, 34, 0, zdec, 4096);
    dec_gates<<<256, 256, 0, stream>>>(zdec, 4, c_d0b, c0, h0);
    gemm_k<<<128, 256, 0, stream>>>(h0, 1024, HPS, h1, 1024, HPS, 1024,
                                    wt_d1h, wt_d1l, 2048, 32, 4, 64, 0, zdec, 4096);
    dec_gates<<<256, 256, 0, stream>>>(zdec, 4, c_d1b, c1, h1);
    qfc_kernel<<<64, 256, 0, stream>>>(h1, wt_qh, wt_ql, wt_fch, wt_fcl, qp, fcp);
    attn_kernel<<<1024, 256, 0, stream>>>(qp, c_bq, Kp, Vp, ctx);
    gemm_k<<<32, 256, 0, stream>>>(ctx, 1024, HPS, ctx, 1024, HPS, 1024,
                                   wt_oh, wt_ol, 1024, 8, 4, 32, 0, qp, 1024);
    reduce_act<<<256, 256, 0, stream>>>(qp, 4, c_bo, attn_h, 0);
    gemm_k<<<32, 256, 0, stream>>>(h1, 1024, HPS, attn_h, 1024, HPS, 1024,
                                   wt_fch, wt_fcl, 2048, 8, 8, 64, 4, fcp, 1024);
    reduce_act<<<256, 256, 0, stream>>>(fcp, 8, c_fcb, comb, 1);
    gemm_k<<<16, 256, 0, stream>>>(comb, 1024, HPS, comb, 1024, HPS, 1024,
                                   wt_outh, wt_outl, 1024, 1, 16, 32, 0, op, 128);
    out_reduce<<<16, 256, 0, stream>>>(op, c_ob, (float*)d_out, xin, s);
  }
}

// Round 3
// 9561.575 us; speedup vs baseline: 1.3672x; 1.3672x over previous
//
#include <hip/hip_runtime.h>
#include <math.h>

// ---------- types ----------
typedef _Float16 h8 __attribute__((ext_vector_type(8)));
typedef _Float16 h4 __attribute__((ext_vector_type(4)));
typedef float f16v __attribute__((ext_vector_type(16)));

#define HPS 262144   // plane stride (elems) for [256][1024] hi/lo activation buffers
#define XPS 2097152  // plane stride for x [256][128][64]
#define IPS 16384    // plane stride for xin [256][64]
#define BSTR 40      // LDS row stride in h16 (80B: 16B-aligned for b128 ops)
#define BUFE (128 * BSTR)  // h16 per LDS buffer: 2 planes * 64 cols * 40

__device__ __forceinline__ float4 ld4(const float* p) { return *(const float4*)p; }
__device__ __forceinline__ float sigf(float x) { return 1.0f / (1.0f + expf(-x)); }
__device__ __forceinline__ float bf2f(unsigned short u) { return __uint_as_float(((unsigned)u) << 16); }
__device__ __forceinline__ float rdin(const void* p, size_t i, int bf) {
  return bf ? bf2f(((const unsigned short*)p)[i]) : ((const float*)p)[i];
}

// ---------- input dtype detector ----------
__global__ void detect_dtype(const unsigned short* __restrict__ probe, int n, int* flag) {
  __shared__ int cnt;
  if (threadIdx.x == 0) cnt = 0;
  __syncthreads();
  int c = 0;
  for (int i = threadIdx.x; i < n; i += 256) {
    int e = (probe[i] >> 7) & 0xFF;
    if (e >= 100 && e <= 126) c++;
  }
  atomicAdd(&cnt, c);
  __syncthreads();
  if (threadIdx.x == 0) *flag = (cnt > (n * 3) / 4) ? 1 : 0;
}

// ---------- dual-mode fp32 convert (biases) ----------
__global__ void cvt_f32(const void* __restrict__ in, float* __restrict__ out, int n,
                        const int* __restrict__ flag) {
  int bf = *flag;
  int i = blockIdx.x * 256 + threadIdx.x;
  if (i < n) out[i] = rdin(in, i, bf);
}

// ---------- transpose + fp16 hi/lo split of weights ----------
__global__ void tsplit(const void* __restrict__ in, int N,
                       _Float16* __restrict__ outHi, _Float16* __restrict__ outLo,
                       int ldo, int kOff, int pOff, const int* __restrict__ flag) {
  __shared__ float tile[32][33];
  int bf = *flag;
  int kb = blockIdx.x * 32, nb = blockIdx.y * 32;
  for (int r = threadIdx.y; r < 32; r += 8)
    tile[threadIdx.x][r] = rdin(in, (size_t)(kb + r) * N + nb + threadIdx.x, bf);
  __syncthreads();
  for (int r = threadIdx.y; r < 32; r += 8) {
    float v = tile[r][threadIdx.x];
    _Float16 hi = (_Float16)v;
    _Float16 lo = (_Float16)(v - (float)hi);
    size_t o = (size_t)(pOff + nb + r) * ldo + kOff + kb + threadIdx.x;
    outHi[o] = hi; outLo[o] = lo;
  }
}

// input -> hi/lo fp16 planes
__global__ void f2h_kernel(const void* __restrict__ in, _Float16* __restrict__ out, int n,
                           const int* __restrict__ flag) {
  int bf = *flag;
  int i = blockIdx.x * 1024 + threadIdx.x * 4;
  if (i < n) {
    float vv[4];
#pragma unroll
    for (int k = 0; k < 4; ++k) vv[k] = rdin(in, i + k, bf);
    h4 hv, lv;
#pragma unroll
    for (int k = 0; k < 4; ++k) { hv[k] = (_Float16)vv[k]; lv[k] = (_Float16)(vv[k] - (float)hv[k]); }
    *(h4*)(out + i) = hv;
    *(h4*)(out + n + i) = lv;
  }
}

__global__ void sentinel_kernel(float* out, float v) { out[0] = v; }

// ---------- core GEMM tile ----------
// PROVEN tile shape (R0 baseline, ~180 VGPR, 20KB LDS -> 2 blocks/CU):
// WG = 256 thr = 4 waves; wave w covers rows [64w, +64), cols [pbase, pbase+64).
// NEW in v3: single barrier per chunk + B staged one chunk ahead through registers
// (double-buffered LDS), so the global B-load latency hides under the MFMAs of the
// previous chunk instead of sitting on the critical path.
// 3 MFMA passes: Ah*Wh + Ah*Wl + Al*Wh (fp32-accurate f16 emulation).
__device__ __forceinline__ void gemm_tile(
    const _Float16* __restrict__ A0, int lda0, int aps0,
    const _Float16* __restrict__ A1, int lda1, int aps1, int ksplit,
    const _Float16* __restrict__ WTh, const _Float16* __restrict__ WTl, int ldw,
    int pbase, int c0, int c1,
    float* __restrict__ zp, int zld, _Float16* Bs /* [2][128][BSTR] */) {
  const int tid = threadIdx.x;
  const int wv = tid >> 6, lane = tid & 63;
  const int l31 = lane & 31, lhi = lane >> 5;

  f16v acc00 = {}, acc01 = {}, acc10 = {}, acc11 = {};

  const int r0 = wv * 64 + l31;
  const int r1 = r0 + 32;
  const _Float16* a0b0 = A0 + (size_t)r0 * lda0;
  const _Float16* a1b0 = A1 + (size_t)r0 * lda1;
  const _Float16* a0b1 = A0 + (size_t)r1 * lda0;
  const _Float16* a1b1 = A1 + (size_t)r1 * lda1;

  // staging roles: 256 thr load 64p x 32k x 2 planes per chunk (32B each)
  const int spl = tid >> 7;               // plane 0 (hi) / 1 (lo)
  const int sidx = tid & 127;
  const int sp = sidx >> 1;               // p row 0..63
  const int skh = (sidx & 1) << 4;        // k offset 0/16
  const _Float16* srow = (spl ? WTl : WTh) + (size_t)(pbase + sp) * ldw + skh;
  const int sdoff = (spl * 64 + sp) * BSTR + skh;

  // prologue: stage chunk c0 into buffer 0
  {
    const _Float16* s = srow + (c0 << 5);
    float4 v0 = *(const float4*)(s);
    float4 v1 = *(const float4*)(s + 8);
    _Float16* d = Bs + sdoff;
    *(float4*)(d) = v0;
    *(float4*)(d + 8) = v1;
  }

  int buf = 0;
  for (int c = c0; c < c1; ++c) {
    __syncthreads();   // Bs[buf] writes visible; prior reads of Bs[buf^1] complete
    float4 n0, n1;
    const bool more = (c + 1 < c1);
    if (more) {
      const _Float16* s = srow + ((c + 1) << 5);
      n0 = *(const float4*)(s);
      n1 = *(const float4*)(s + 8);
    }
    const _Float16* bb = Bs + buf * BUFE;
    int k0 = c << 5;
#pragma unroll
    for (int sub = 0; sub < 2; ++sub) {
      int ks = k0 + sub * 16 + lhi * 8;
      const _Float16 *pa0, *pa1; int ap;
      if (ks < ksplit) { pa0 = a0b0 + ks; pa1 = a0b1 + ks; ap = aps0; }
      else { int kk = ks - ksplit; pa0 = a1b0 + kk; pa1 = a1b1 + kk; ap = aps1; }
      h8 af0h = *(const h8*)pa0;
      h8 af0l = *(const h8*)(pa0 + ap);
      h8 af1h = *(const h8*)pa1;
      h8 af1l = *(const h8*)(pa1 + ap);
      int kl = sub * 16 + lhi * 8;
      h8 b0h = *(const h8*)(bb + (size_t)(l31) * BSTR + kl);
      h8 b0l = *(const h8*)(bb + (size_t)(64 + l31) * BSTR + kl);
      h8 b1h = *(const h8*)(bb + (size_t)(32 + l31) * BSTR + kl);
      h8 b1l = *(const h8*)(bb + (size_t)(96 + l31) * BSTR + kl);
      acc00 = __builtin_amdgcn_mfma_f32_32x32x16_f16(af0h, b0h, acc00, 0, 0, 0);
      acc00 = __builtin_amdgcn_mfma_f32_32x32x16_f16(af0h, b0l, acc00, 0, 0, 0);
      acc00 = __builtin_amdgcn_mfma_f32_32x32x16_f16(af0l, b0h, acc00, 0, 0, 0);
      acc01 = __builtin_amdgcn_mfma_f32_32x32x16_f16(af0h, b1h, acc01, 0, 0, 0);
      acc01 = __builtin_amdgcn_mfma_f32_32x32x16_f16(af0h, b1l, acc01, 0, 0, 0);
      acc01 = __builtin_amdgcn_mfma_f32_32x32x16_f16(af0l, b1h, acc01, 0, 0, 0);
      acc10 = __builtin_amdgcn_mfma_f32_32x32x16_f16(af1h, b0h, acc10, 0, 0, 0);
      acc10 = __builtin_amdgcn_mfma_f32_32x32x16_f16(af1h, b0l, acc10, 0, 0, 0);
      acc10 = __builtin_amdgcn_mfma_f32_32x32x16_f16(af1l, b0h, acc10, 0, 0, 0);
      acc11 = __builtin_amdgcn_mfma_f32_32x32x16_f16(af1h, b1h, acc11, 0, 0, 0);
      acc11 = __builtin_amdgcn_mfma_f32_32x32x16_f16(af1h, b1l, acc11, 0, 0, 0);
      acc11 = __builtin_amdgcn_mfma_f32_32x32x16_f16(af1l, b1h, acc11, 0, 0, 0);
    }
    if (more) {
      _Float16* d = Bs + (buf ^ 1) * BUFE + sdoff;
      *(float4*)(d) = n0;
      *(float4*)(d + 8) = n1;
    }
    buf ^= 1;
  }

  // epilogue. C/D layout (verified m74/m101): col = lane&31, row = (reg&3)+8*(reg>>2)+4*(lane>>5)
#pragma unroll
  for (int mi = 0; mi < 2; ++mi) {
#pragma unroll
    for (int ni = 0; ni < 2; ++ni) {
      f16v av = (mi == 0) ? (ni == 0 ? acc00 : acc01) : (ni == 0 ? acc10 : acc11);
      int col = pbase + ni * 32 + l31;
#pragma unroll
      for (int r = 0; r < 16; ++r) {
        int row = wv * 64 + mi * 32 + (r & 3) + ((r >> 2) * 8) + lhi * 4;
        zp[(size_t)row * zld + col] = av[r];
      }
    }
  }
}

// ---------- encoder GEMM: L1(t-1) first (longest chains), then L0(t), then KV(t-2) ----------
// 448 blocks at l1kq=4 (64*4 + 128 + 64), all chains 16-17 chunks -> balanced CU load.
__global__ __launch_bounds__(256, 2) void enc_gemm(int t, int l1kq,
    const _Float16* xh, const _Float16* h0, const _Float16* h1,
    const _Float16* wt0h, const _Float16* wt0l,
    const _Float16* wt1h, const _Float16* wt1l,
    const _Float16* wtkvh, const _Float16* wtkvl,
    float* z0, float* z1, float* kvz) {
  __shared__ _Float16 Bs[2 * BUFE];
  int blk = blockIdx.x;
  int nl1 = 64 * l1kq;
  if (blk < nl1) {                       // L1, timestep t-1
    if (t < 1 || t > 128) return;
    int pg = blk & 63, kq = blk >> 6;
    int c0 = (64 * kq) / l1kq, c1 = (64 * (kq + 1)) / l1kq;
    gemm_tile(h0, 1024, HPS, h1, 1024, HPS, 1024, wt1h, wt1l, 2048,
              pg * 64, c0, c1, z1 + (size_t)kq * 1048576, 4096, Bs);
  } else if (blk < nl1 + 128) {          // L0, timestep t
    if (t > 127) return;
    int w = blk - nl1, pg = w & 63, kq = w >> 6;
    gemm_tile(xh + (size_t)t * 64, 8192, XPS, h0, 1024, HPS, 64, wt0h, wt0l, 1088,
              pg * 64, kq * 17, kq * 17 + 17, z0 + (size_t)kq * 1048576, 4096, Bs);
  } else {                               // KV, timestep t-2
    if (t < 2) return;
    int w = blk - nl1 - 128, pg = w & 31, kq = w >> 5;
    gemm_tile(h1, 1024, HPS, h1, 1024, HPS, 1024, wtkvh, wtkvl, 1024,
              pg * 64, kq * 16, kq * 16 + 16, kvz + (size_t)kq * 524288, 2048, Bs);
  }
}

// ---------- generic K-split GEMM (decoder stages) ----------
__global__ __launch_bounds__(256, 2) void gemm_k(
    const _Float16* A0, int lda0, int aps0,
    const _Float16* A1, int lda1, int aps1, int ksplit,
    const _Float16* WTh, const _Float16* WTl, int ldw,
    int npg, int nkq, int tot, int kqoff, float* zp, int zld) {
  __shared__ _Float16 Bs[2 * BUFE];
  int pg = blockIdx.x % npg, kq = blockIdx.x / npg + kqoff;
  int c0 = (tot * kq) / nkq, c1 = (tot * (kq + 1)) / nkq;
  gemm_tile(A0, lda0, aps0, A1, lda1, aps1, ksplit, WTh, WTl, ldw,
            pg * 64, c0, c1, zp + (size_t)kq * 256 * zld, zld, Bs);
}

// ---------- fused q-projection + fc top-half (both depend only on dh1) ----------
__global__ __launch_bounds__(256, 2) void qfc_kernel(
    const _Float16* h1,
    const _Float16* wqh, const _Float16* wql,
    const _Float16* wfh, const _Float16* wfl,
    float* qp, float* fcp) {
  __shared__ _Float16 Bs[2 * BUFE];
  int blk = blockIdx.x;
  if (blk < 64) {           // q = dh1 @ Wq : N=1024, K=1024
    int pg = blk & 15, kq = blk >> 4;
    gemm_tile(h1, 1024, HPS, h1, 1024, HPS, 1024, wqh, wql, 1024,
              pg * 64, kq * 8, kq * 8 + 8, qp + (size_t)kq * 262144, 1024, Bs);
  } else {                  // fc top: chunks [0,32) = dh1 half of fc_W (parts 0..3)
    int w = blk - 64, pg = w & 15, kq = w >> 4;
    gemm_tile(h1, 1024, HPS, h1, 1024, HPS, 1024, wfh, wfl, 2048,
              pg * 64, kq * 8, kq * 8 + 8, fcp + (size_t)kq * 262144, 1024, Bs);
  }
}

// ---------- LSTM gate pointwise ----------
__device__ __forceinline__ void gates_body(const float* __restrict__ zp, int nparts,
    const float* __restrict__ bias, float* __restrict__ c,
    _Float16* __restrict__ h, int blk) {
  int e = blk * 1024 + threadIdx.x * 4;
  int b = e >> 10, j = e & 1023;
  size_t zrow = (size_t)b * 4096;
  float4 vi = ld4(bias + j), vf = ld4(bias + 1024 + j), vg = ld4(bias + 2048 + j), vo = ld4(bias + 3072 + j);
  for (int q = 0; q < nparts; ++q) {
    const float* zq = zp + (size_t)q * 1048576 + zrow;
    float4 t;
    t = ld4(zq + j);        vi.x += t.x; vi.y += t.y; vi.z += t.z; vi.w += t.w;
    t = ld4(zq + 1024 + j); vf.x += t.x; vf.y += t.y; vf.z += t.z; vf.w += t.w;
    t = ld4(zq + 2048 + j); vg.x += t.x; vg.y += t.y; vg.z += t.z; vg.w += t.w;
    t = ld4(zq + 3072 + j); vo.x += t.x; vo.y += t.y; vo.z += t.z; vo.w += t.w;
  }
  float* cp = c + (size_t)b * 1024 + j;
  float4 cv = ld4(cp);
  float zi[4] = {vi.x, vi.y, vi.z, vi.w}, zf[4] = {vf.x, vf.y, vf.z, vf.w};
  float zg[4] = {vg.x, vg.y, vg.z, vg.w}, zo[4] = {vo.x, vo.y, vo.z, vo.w};
  float cc[4] = {cv.x, cv.y, cv.z, cv.w};
  float hn[4];
#pragma unroll
  for (int k = 0; k < 4; ++k) {
    float ii = sigf(zi[k]), ff = sigf(zf[k]), gg = tanhf(zg[k]), oo = sigf(zo[k]);
    float cn = ff * cc[k] + ii * gg;
    cc[k] = cn;
    hn[k] = oo * tanhf(cn);
  }
  float4 co; co.x = cc[0]; co.y = cc[1]; co.z = cc[2]; co.w = cc[3];
  *(float4*)cp = co;
  h4 hv, lv;
#pragma unroll
  for (int k = 0; k < 4; ++k) { hv[k] = (_Float16)hn[k]; lv[k] = (_Float16)(hn[k] - (float)hv[k]); }
  *(h4*)(h + (size_t)b * 1024 + j) = hv;
  *(h4*)(h + HPS + (size_t)b * 1024 + j) = lv;
}

// grid 1024: [0,256) L0 gates, [256,512) L1 gates, [512,1024) KV bias+fp16 store
__global__ void enc_gates(int t, int l1parts, const float* z0, const float* z1, const float* kvz,
                          const float* b0, const float* b1,
                          const float* bk, const float* bv,
                          float* c0, float* c1, _Float16* h0, _Float16* h1,
                          _Float16* Kp, _Float16* Vp) {
  int blk = blockIdx.x;
  if (blk < 256) {
    if (t > 127) return;
    gates_body(z0, 2, b0, c0, h0, blk);
  } else if (blk < 512) {
    if (t < 1 || t > 128) return;
    gates_body(z1, l1parts, b1, c1, h1, blk - 256);
  } else {
    if (t < 2) return;
    int e = (blk - 512) * 1024 + threadIdx.x * 4;   // [0, 524288) = [256][2048]
    int b = e >> 11, col = e & 2047;
    const float* bb = (col < 1024) ? (bk + col) : (bv + col - 1024);
    float4 v = ld4(bb);
    for (int q = 0; q < 2; ++q) {
      float4 tt = ld4(kvz + (size_t)q * 524288 + e);
      v.x += tt.x; v.y += tt.y; v.z += tt.z; v.w += tt.w;
    }
    _Float16* dst = (col < 1024) ? Kp : Vp;
    int cc = (col < 1024) ? col : col - 1024;
    h4 hv; hv[0] = (_Float16)v.x; hv[1] = (_Float16)v.y; hv[2] = (_Float16)v.z; hv[3] = (_Float16)v.w;
    *(h4*)(dst + (size_t)(b * 128 + (t - 2)) * 1024 + cc) = hv;
  }
}

__global__ void dec_gates(const float* zp, int nparts, const float* bias,
                          float* c, _Float16* h) {
  gates_body(zp, nparts, bias, c, h, blockIdx.x);
}

// ---------- reduce + bias (+relu) -> hi/lo fp16, cols = 1024 ----------
__global__ void reduce_act(const float* __restrict__ zp, int nparts,
                           const float* __restrict__ bias, _Float16* __restrict__ out, int relu) {
  int e = blockIdx.x * 1024 + threadIdx.x * 4;
  int j = e & 1023;
  float4 v = ld4(bias + j);
  for (int q = 0; q < nparts; ++q) {
    float4 t = ld4(zp + (size_t)q * 262144 + e);
    v.x += t.x; v.y += t.y; v.z += t.z; v.w += t.w;
  }
  if (relu) {
    v.x = fmaxf(v.x, 0.f); v.y = fmaxf(v.y, 0.f); v.z = fmaxf(v.z, 0.f); v.w = fmaxf(v.w, 0.f);
  }
  float vv[4] = {v.x, v.y, v.z, v.w};
  h4 hv, lv;
#pragma unroll
  for (int k = 0; k < 4; ++k) { hv[k] = (_Float16)vv[k]; lv[k] = (_Float16)(vv[k] - (float)hv[k]); }
  *(h4*)(out + e) = hv;
  *(h4*)(out + HPS + e) = lv;
}

// ---------- final output: reduce 16 parts + bias -> d_out (fp32) + xin hi/lo ----------
__global__ void out_reduce(const float* __restrict__ op, const float* __restrict__ outb,
                           float* __restrict__ dout, _Float16* __restrict__ xin, int s) {
  int e = blockIdx.x * 1024 + threadIdx.x * 4;  // 16 blocks -> 16384 elems
  int b = e >> 6, o = e & 63;
  float4 v = ld4(outb + o);
  for (int q = 0; q < 16; ++q) {
    float4 t = ld4(op + (size_t)q * 16384 + e);
    v.x += t.x; v.y += t.y; v.z += t.z; v.w += t.w;
  }
  *(float4*)(dout + (size_t)(b * 16 + s) * 64 + o) = v;   // d_out is fp32
  float vv[4] = {v.x, v.y, v.z, v.w};
  h4 hv, lv;
#pragma unroll
  for (int k = 0; k < 4; ++k) { hv[k] = (_Float16)vv[k]; lv[k] = (_Float16)(vv[k] - (float)hv[k]); }
  *(h4*)(xin + e) = hv;
  *(h4*)(xin + IPS + e) = lv;
}

// ---------- fused attention ----------
__global__ void attn_kernel(const float* __restrict__ qp, const float* __restrict__ bq,
                            const _Float16* __restrict__ Kp, const _Float16* __restrict__ Vp,
                            _Float16* __restrict__ ctx) {
  int b = blockIdx.x >> 2, n = blockIdx.x & 3;
  __shared__ float qs[256];
  __shared__ float sw[128];
  int tid = threadIdx.x;
  float qv = bq[n * 256 + tid];
  for (int q = 0; q < 4; ++q) qv += qp[(size_t)q * 262144 + (size_t)b * 1024 + n * 256 + tid];
  qs[tid] = qv;
  __syncthreads();
  int w = tid >> 6, lane = tid & 63;
  for (int s = w; s < 128; s += 4) {
    const _Float16* kr = Kp + (size_t)(b * 128 + s) * 1024 + n * 256;
    float acc = 0.f;
#pragma unroll
    for (int d = 0; d < 4; ++d) acc += qs[lane + d * 64] * (float)kr[lane + d * 64];
    for (int off = 32; off; off >>= 1) acc += __shfl_down(acc, off);
    if (lane == 0) sw[s] = acc * 0.0625f;  // / sqrt(256)
  }
  __syncthreads();
  if (w == 0) {
    float a = sw[lane], bb = sw[lane + 64];
    float m = fmaxf(a, bb);
    for (int off = 32; off; off >>= 1) m = fmaxf(m, __shfl_down(m, off));
    m = __shfl(m, 0);
    float e1 = expf(a - m), e2 = expf(bb - m);
    float ss = e1 + e2;
    for (int off = 32; off; off >>= 1) ss += __shfl_down(ss, off);
    ss = __shfl(ss, 0);
    float inv = 1.0f / ss;
    sw[lane] = e1 * inv; sw[lane + 64] = e2 * inv;
  }
  __syncthreads();
  float acc = 0.f;
  const _Float16* vb = Vp + (size_t)b * 131072 + n * 256 + tid;
  for (int s2 = 0; s2 < 128; ++s2) acc += sw[s2] * (float)vb[(size_t)s2 * 1024];
  size_t idx = (size_t)b * 1024 + n * 256 + tid;
  _Float16 hi = (_Float16)acc;
  ctx[idx] = hi;
  ctx[HPS + idx] = (_Float16)(acc - (float)hi);
}

// ---------- host ----------
extern "C" void kernel_launch(void* const* d_in, const int* in_sizes, int n_in,
                              void* d_out, int out_size, void* d_ws, size_t ws_size,
                              hipStream_t stream) {
  const void* x     = d_in[0];
  const void* e0_Wx = d_in[1];
  const void* e0_Wh = d_in[2];
  const void* e0_b  = d_in[3];
  const void* e1_Wx = d_in[4];
  const void* e1_Wh = d_in[5];
  const void* e1_b  = d_in[6];
  const void* d0_Wx = d_in[7];
  const void* d0_Wh = d_in[8];
  const void* d0_b  = d_in[9];
  const void* d1_Wx = d_in[10];
  const void* d1_Wh = d_in[11];
  const void* d1_b  = d_in[12];
  const void* Wq = d_in[13];
  const void* Wk = d_in[14];
  const void* Wv = d_in[15];
  const void* Wo = d_in[16];
  const void* bq = d_in[17];
  const void* bk = d_in[18];
  const void* bv = d_in[19];
  const void* bo = d_in[20];
  const void* fc_W  = d_in[21];
  const void* fc_b  = d_in[22];
  const void* out_W = d_in[23];
  const void* out_b = d_in[24];

  // Layout (retry with smaller L1 K-split if workspace is tight)
  int l1parts = 4;
  char* p = (char*)d_ws;
  int* flag; float* bias_arena; char* warena; char* zero0;
  _Float16 *h0, *h1, *xin, *Kp, *Vp, *ctx, *attn_h, *comb;
  float *c0, *c1; float* zarena;
  size_t zeroBytes = 0;

  for (int attempt = 0; attempt < 2; ++attempt) {
    p = (char*)d_ws;
    auto alloc = [&](size_t bytes) { char* r = p; p += (bytes + 255) & ~(size_t)255; return r; };
    flag = (int*)alloc(256);
    bias_arena = (float*)alloc(87040);
    warena = alloc(68419584);
    zero0 = p;
    h0 = (_Float16*)alloc(1048576);
    h1 = (_Float16*)alloc(1048576);
    c0 = (float*)alloc(1048576);
    c1 = (float*)alloc(1048576);
    xin = (_Float16*)alloc(65536);
    zeroBytes = (size_t)(p - zero0);
    Kp = (_Float16*)alloc(67108864);
    Vp = (_Float16*)alloc(67108864);
    zarena = (float*)alloc((size_t)(3 + l1parts) * 4194304);
    ctx    = (_Float16*)alloc(1048576);
    attn_h = (_Float16*)alloc(1048576);
    comb   = (_Float16*)alloc(1048576);
    if ((size_t)(p - (char*)d_ws) <= ws_size) break;
    l1parts = 2;
  }
  if ((size_t)(p - (char*)d_ws) > ws_size) {
    sentinel_kernel<<<1, 1, 0, stream>>>((float*)d_out, 1.0e9f + (float)ws_size);
    return;
  }

  float* c_e0b = bias_arena +     0;
  float* c_e1b = bias_arena +  4096;
  float* c_d0b = bias_arena +  8192;
  float* c_d1b = bias_arena + 12288;
  float* c_bq  = bias_arena + 16384;
  float* c_bk  = bias_arena + 17408;
  float* c_bv  = bias_arena + 18432;
  float* c_bo  = bias_arena + 19456;
  float* c_fcb = bias_arena + 20480;
  float* c_ob  = bias_arena + 21504;

  _Float16* wt_e0h = (_Float16*)(warena);
  _Float16* wt_e0l = (_Float16*)(warena +  8912896);
  _Float16* wt_e1h = (_Float16*)(warena + 17825792);
  _Float16* wt_e1l = (_Float16*)(warena + 34603008);
  _Float16* wt_kvh = (_Float16*)(warena + 51380224);
  _Float16* wt_kvl = (_Float16*)(warena + 55574528);
  _Float16* xh     = (_Float16*)(warena + 59768832);
  _Float16* wt_d0h = (_Float16*)(warena);
  _Float16* wt_d0l = (_Float16*)(warena +  8912896);
  _Float16* wt_d1h = (_Float16*)(warena + 17825792);
  _Float16* wt_d1l = (_Float16*)(warena + 34603008);
  _Float16* wt_qh  = (_Float16*)(warena + 51380224);
  _Float16* wt_ql  = (_Float16*)(warena + 53477376);
  _Float16* wt_oh  = (_Float16*)(warena + 55574528);
  _Float16* wt_ol  = (_Float16*)(warena + 57671680);
  _Float16* wt_fch = (_Float16*)(warena + 59768832);
  _Float16* wt_fcl = (_Float16*)(warena + 63963136);
  _Float16* wt_outh= (_Float16*)(warena + 68157440);
  _Float16* wt_outl= (_Float16*)(warena + 68288512);

  float* z0e = zarena;                               // enc L0: 2 parts x 1,048,576 floats
  float* z1e = zarena + 2097152;                     // enc L1: l1parts parts
  float* kvz = z1e + (size_t)l1parts * 1048576;      // enc KV: 2 parts x 524,288 floats
  float* zdec = zarena;                              // dec d0/d1: 4 parts x 1,048,576 floats
  float* fcp = zarena;                               // 8 parts x 262,144 floats
  float* qp  = zarena + 2097152;                     // 4 parts x 262,144 floats
  float* op  = zarena + 3145728;                     // 16 parts x 16,384 floats

  // dtype detection + bias conversion
  detect_dtype<<<1, 256, 0, stream>>>((const unsigned short*)e0_Wx, 16384, flag);
  cvt_f32<<<16, 256, 0, stream>>>(e0_b, c_e0b, 4096, flag);
  cvt_f32<<<16, 256, 0, stream>>>(e1_b, c_e1b, 4096, flag);
  cvt_f32<<<16, 256, 0, stream>>>(d0_b, c_d0b, 4096, flag);
  cvt_f32<<<16, 256, 0, stream>>>(d1_b, c_d1b, 4096, flag);
  cvt_f32<<<4, 256, 0, stream>>>(bq, c_bq, 1024, flag);
  cvt_f32<<<4, 256, 0, stream>>>(bk, c_bk, 1024, flag);
  cvt_f32<<<4, 256, 0, stream>>>(bv, c_bv, 1024, flag);
  cvt_f32<<<4, 256, 0, stream>>>(bo, c_bo, 1024, flag);
  cvt_f32<<<4, 256, 0, stream>>>(fc_b, c_fcb, 1024, flag);
  cvt_f32<<<1, 64, 0, stream>>>(out_b, c_ob, 64, flag);

  dim3 tb(32, 8);
  // encoder weight prep
  tsplit<<<dim3(2, 128), tb, 0, stream>>>(e0_Wx, 4096, wt_e0h, wt_e0l, 1088, 0, 0, flag);
  tsplit<<<dim3(32, 128), tb, 0, stream>>>(e0_Wh, 4096, wt_e0h, wt_e0l, 1088, 64, 0, flag);
  tsplit<<<dim3(32, 128), tb, 0, stream>>>(e1_Wx, 4096, wt_e1h, wt_e1l, 2048, 0, 0, flag);
  tsplit<<<dim3(32, 128), tb, 0, stream>>>(e1_Wh, 4096, wt_e1h, wt_e1l, 2048, 1024, 0, flag);
  tsplit<<<dim3(32, 32), tb, 0, stream>>>(Wk, 1024, wt_kvh, wt_kvl, 1024, 0, 0, flag);
  tsplit<<<dim3(32, 32), tb, 0, stream>>>(Wv, 1024, wt_kvh, wt_kvl, 1024, 0, 1024, flag);
  f2h_kernel<<<2048, 256, 0, stream>>>(x, xh, 2097152, flag);
  hipMemsetAsync(zero0, 0, zeroBytes, stream);

  // encoder: L1(t-1) || L0(t) || KV(t-2) pipelined
  int encBlocks = 64 * l1parts + 192;
  for (int t = 0; t <= 129; ++t) {
    enc_gemm<<<encBlocks, 256, 0, stream>>>(t, l1parts, xh, h0, h1,
                                            wt_e0h, wt_e0l, wt_e1h, wt_e1l,
                                            wt_kvh, wt_kvl, z0e, z1e, kvz);
    enc_gates<<<1024, 256, 0, stream>>>(t, l1parts, z0e, z1e, kvz, c_e0b, c_e1b, c_bk, c_bv,
                                        c0, c1, h0, h1, Kp, Vp);
  }

  // decoder weight prep (overwrites encoder weights; stream-ordered)
  tsplit<<<dim3(2, 128), tb, 0, stream>>>(d0_Wx, 4096, wt_d0h, wt_d0l, 1088, 0, 0, flag);
  tsplit<<<dim3(32, 128), tb, 0, stream>>>(d0_Wh, 4096, wt_d0h, wt_d0l, 1088, 64, 0, flag);
  tsplit<<<dim3(32, 128), tb, 0, stream>>>(d1_Wx, 4096, wt_d1h, wt_d1l, 2048, 0, 0, flag);
  tsplit<<<dim3(32, 128), tb, 0, stream>>>(d1_Wh, 4096, wt_d1h, wt_d1l, 2048, 1024, 0, flag);
  tsplit<<<dim3(32, 32), tb, 0, stream>>>(Wq, 1024, wt_qh, wt_ql, 1024, 0, 0, flag);
  tsplit<<<dim3(32, 32), tb, 0, stream>>>(Wo, 1024, wt_oh, wt_ol, 1024, 0, 0, flag);
  tsplit<<<dim3(64, 32), tb, 0, stream>>>(fc_W, 1024, wt_fch, wt_fcl, 2048, 0, 0, flag);
  tsplit<<<dim3(32, 2), tb, 0, stream>>>(out_W, 64, wt_outh, wt_outl, 1024, 0, 0, flag);

  // decoder: 16 steps
  for (int s = 0; s < 16; ++s) {
    gemm_k<<<256, 256, 0, stream>>>(xin, 64, IPS, h0, 1024, HPS, 64,
                                    wt_d0h, wt_d0l, 1088, 64, 4, 34, 0, zdec, 4096);
    dec_gates<<<256, 256, 0, stream>>>(zdec, 4, c_d0b, c0, h0);
    gemm_k<<<256, 256, 0, stream>>>(h0, 1024, HPS, h1, 1024, HPS, 1024,
                                    wt_d1h, wt_d1l, 2048, 64, 4, 64, 0, zdec, 4096);
    dec_gates<<<256, 256, 0, stream>>>(zdec, 4, c_d1b, c1, h1);
    qfc_kernel<<<128, 256, 0, stream>>>(h1, wt_qh, wt_ql, wt_fch, wt_fcl, qp, fcp);
    attn_kernel<<<1024, 256, 0, stream>>>(qp, c_bq, Kp, Vp, ctx);
    gemm_k<<<64, 256, 0, stream>>>(ctx, 1024, HPS, ctx, 1024, HPS, 1024,
                                   wt_oh, wt_ol, 1024, 16, 4, 32, 0, qp, 1024);
    reduce_act<<<256, 256, 0, stream>>>(qp, 4, c_bo, attn_h, 0);
    gemm_k<<<64, 256, 0, stream>>>(h1, 1024, HPS, attn_h, 1024, HPS, 1024,
                                   wt_fch, wt_fcl, 2048, 16, 8, 64, 4, fcp, 1024);
    reduce_act<<<256, 256, 0, stream>>>(fcp, 8, c_fcb, comb, 1);
    gemm_k<<<16, 256, 0, stream>>>(comb, 1024, HPS, comb, 1024, HPS, 1024,
                                   wt_outh, wt_outl, 1024, 1, 16, 32, 0, op, 64);
    out_reduce<<<16, 256, 0, stream>>>(op, c_ob, (float*)d_out, xin, s);
  }
}